// Round 7
// baseline (441.061 us; speedup 1.0000x reference)
//
#include <hip/hip_runtime.h>
#include <hip/hip_bf16.h>

#define NEG_INF_F (-4294967295.0f)  // -(2^32)+1, matches reference padding

typedef __attribute__((ext_vector_type(8))) short bf16x8;   // MFMA A/B frag (4 VGPRs)
typedef __attribute__((ext_vector_type(4))) float f32x4;    // MFMA C/D frag

__device__ __forceinline__ unsigned short f2bf(float x) {
    unsigned u = __float_as_uint(x);
    return (unsigned short)((u + 0x7fffu + ((u >> 16) & 1u)) >> 16);  // RNE
}
__device__ __forceinline__ unsigned f2bf2(float a, float b) {
    __hip_bfloat162 h2 = __float22bfloat162_rn(make_float2(a, b));
    unsigned r; __builtin_memcpy(&r, &h2, 4); return r;
}
union FragU { unsigned u[4]; bf16x8 h; };

// ============ kernel A: precompute c_all[2048,64] and M_all[2048,8192] =======
// M_all is stored as the EXACT swizzled LDS image the main kernel uses:
// element (n, pos p in [0,16), j in [0,8)) at b*8192 + n*128 + p*8 + j holds
// M[k][n] with k = (p ^ (n&15))*8 + j, M = (W1k - W1d) + diag(q)*W1p (bf16).
struct SmemA { float q[128]; float cpart[256]; };

__global__ __launch_bounds__(256)
void precompute_cm(const float* __restrict__ Q, const float* __restrict__ W1,
                   const float* __restrict__ b1,
                   float* __restrict__ c_all, unsigned short* __restrict__ M_all)
{
    __shared__ SmemA sm;
    const int b = blockIdx.x;
    const int tid = threadIdx.x;
    if (tid < 128) sm.q[tid] = Q[b * 128 + tid];
    __syncthreads();

    // c partials: wave kc covers 32 k's
    {
        const int n = tid & 63, kc = tid >> 6;
        float acc = (kc == 0) ? b1[n] : 0.0f;
        #pragma unroll 4
        for (int i = 0; i < 32; ++i) {
            const int k = kc * 32 + i;
            acc += sm.q[k] * (W1[k * 64 + n] + W1[(256 + k) * 64 + n]);
        }
        sm.cpart[kc * 64 + n] = acc;
    }

    // M image: 1024 16-byte granules, coalesced writes
    #pragma unroll
    for (int i = 0; i < 4; ++i) {
        const int pos = tid + i * 256;
        const int n   = pos >> 4;
        const int p   = pos & 15;
        const int kb  = (p ^ (n & 15)) * 8;
        unsigned u[4];
        #pragma unroll
        for (int j = 0; j < 4; ++j) {
            const int k0 = kb + 2 * j, k1 = k0 + 1;
            const float v0 = (W1[(128 + k0) * 64 + n] - W1[(256 + k0) * 64 + n])
                           + sm.q[k0] * W1[(384 + k0) * 64 + n];
            const float v1 = (W1[(128 + k1) * 64 + n] - W1[(256 + k1) * 64 + n])
                           + sm.q[k1] * W1[(384 + k1) * 64 + n];
            u[j] = f2bf2(v0, v1);
        }
        uint4 pk = make_uint4(u[0], u[1], u[2], u[3]);
        *reinterpret_cast<uint4*>(&M_all[(size_t)b * 8192 + pos * 8]) = pk;
    }
    __syncthreads();
    if (tid < 64)
        c_all[b * 64 + tid] = sm.cpart[tid] + sm.cpart[64 + tid]
                            + sm.cpart[128 + tid] + sm.cpart[192 + tid];
}

// ============ kernel B: streaming one-pass attention ========================
struct __align__(16) Smem {
    unsigned short Mt[64 * 128];    // 16384 B  M image (copied from M_all)
    unsigned short h1s[4][16 * 64]; //  8192 B  per-wave h1 C->A scratch
    float Om[4][128];               //  2048 B  per-wave pooled partials
    float mw[4], lw[4];             //    32 B  per-wave online-softmax state
};

// (256,3): VGPR cap 170 (2nd arg = min BLOCKS/CU on this toolchain, R3 evidence).
// Prefetch regs push natural VGPR to ~150 -> 12 waves/CU, no spill.
__global__ __launch_bounds__(256, 3)
void attn_main(const float* __restrict__ Kg,   // [2048,200,128]
               const int*   __restrict__ kid,  // [2048,200]
               const float* __restrict__ W2,   // [64,32]
               const float* __restrict__ b2,   // [32]
               const float* __restrict__ W3,   // [32,1]
               const float* __restrict__ b3,   // [1]
               const float* __restrict__ c_all,
               const unsigned short* __restrict__ M_all,
               float* __restrict__ out)        // [2048,128]
{
    __shared__ Smem sm;
    const int b    = blockIdx.x;
    const int tid  = threadIdx.x;
    const int wave = tid >> 6;
    const int lane = tid & 63;
    const int l15  = lane & 15;
    const int quad = lane >> 4;

    // ---- setup: copy M image (16 KB, coalesced), scalar param loads ----
    {
        const uint4* msrc = reinterpret_cast<const uint4*>(M_all + (size_t)b * 8192);
        #pragma unroll
        for (int i = 0; i < 4; ++i) {
            const int pos = tid + i * 256;
            *reinterpret_cast<uint4*>(&sm.Mt[pos * 8]) = msrc[pos];
        }
    }
    bf16x8 W2f[2][2];
    #pragma unroll
    for (int ks = 0; ks < 2; ++ks) {
        #pragma unroll
        for (int nt = 0; nt < 2; ++nt) {
            const int n = nt * 16 + l15;
            const int kb = ks * 32 + quad * 8;
            bf16x8 f;
            #pragma unroll
            for (int j = 0; j < 8; ++j) f[j] = (short)f2bf(W2[(kb + j) * 32 + n]);
            W2f[ks][nt] = f;
        }
    }
    const float w3a = W3[l15],  w3b = W3[16 + l15];
    const float b2a = b2[l15],  b2b = b2[16 + l15];
    const float b3v = b3[0];
    float cn[4];
    #pragma unroll
    for (int nt = 0; nt < 4; ++nt) cn[nt] = c_all[b * 64 + nt * 16 + l15];
    __syncthreads();   // M image visible

    const float* kbase = Kg + (size_t)b * 25600;
    unsigned short* h1w = &sm.h1s[wave][0];
    const f32x4 zero4 = {0.f, 0.f, 0.f, 0.f};

    float O[32];
    #pragma unroll
    for (int i = 0; i < 32; ++i) O[i] = 0.0f;
    float mrun = -__builtin_inff(), lrun = 0.0f;

    // ---- pipelined tile loop: wave w does tiles w, w+4, w+8 (w==0 also 12) ----
    float4 kaA[4], kbA[4]; int kidA;
    {
        const int tr = min(wave * 16 + l15, 199);
        const float* kr = kbase + tr * 128;
        #pragma unroll
        for (int ks = 0; ks < 4; ++ks) {
            kaA[ks] = *reinterpret_cast<const float4*>(kr + ks * 32 + quad * 8);
            kbA[ks] = *reinterpret_cast<const float4*>(kr + ks * 32 + quad * 8 + 4);
        }
        kidA = kid[b * 200 + tr];
    }

    for (int tile = wave; tile < 13; tile += 4) {
        // prefetch next tile while computing this one
        float4 kaB[4], kbB[4]; int kidB = 0;
        const int nx = tile + 4;
        if (nx < 13) {
            const int tr = min(nx * 16 + l15, 199);
            const float* kr = kbase + tr * 128;
            #pragma unroll
            for (int ks = 0; ks < 4; ++ks) {
                kaB[ks] = *reinterpret_cast<const float4*>(kr + ks * 32 + quad * 8);
                kbB[ks] = *reinterpret_cast<const float4*>(kr + ks * 32 + quad * 8 + 4);
            }
            kidB = kid[b * 200 + tr];
        }

        const int t0 = tile * 16;
        const int t  = t0 + l15;
        f32x4 acc[4] = {zero4, zero4, zero4, zero4};
        #pragma unroll
        for (int ks = 0; ks < 4; ++ks) {
            FragU A;
            A.u[0] = f2bf2(kaA[ks].x, kaA[ks].y);
            A.u[1] = f2bf2(kaA[ks].z, kaA[ks].w);
            A.u[2] = f2bf2(kbA[ks].x, kbA[ks].y);
            A.u[3] = f2bf2(kbA[ks].z, kbA[ks].w);
            #pragma unroll
            for (int nt = 0; nt < 4; ++nt) {
                const int n = nt * 16 + l15;
                const int g = (ks * 4 + quad) ^ l15;
                const bf16x8 Bf = *reinterpret_cast<const bf16x8*>(&sm.Mt[n * 128 + g * 8]);
                acc[nt] = __builtin_amdgcn_mfma_f32_16x16x32_bf16(A.h, Bf, acc[nt], 0, 0, 0);
            }
        }
        // epilogue: + c[n], relu, bf16 -> wave-private scratch in A-layout
        #pragma unroll
        for (int nt = 0; nt < 4; ++nt) {
            const int n = nt * 16 + l15;
            #pragma unroll
            for (int r = 0; r < 4; ++r) {
                const int m = quad * 4 + r;
                const float h = fmaxf(acc[nt][r] + cn[nt], 0.0f);
                const int g = (n >> 3) ^ (m & 7);
                h1w[m * 64 + g * 8 + (n & 7)] = f2bf(h);
            }
        }
        // layer 2: [16,64] @ [64,32]
        f32x4 p0 = zero4, p1 = zero4;
        #pragma unroll
        for (int ks = 0; ks < 2; ++ks) {
            const int g = (ks * 4 + quad) ^ (l15 & 7);
            const bf16x8 A2l = *reinterpret_cast<const bf16x8*>(&h1w[l15 * 64 + g * 8]);
            p0 = __builtin_amdgcn_mfma_f32_16x16x32_bf16(A2l, W2f[ks][0], p0, 0, 0, 0);
            p1 = __builtin_amdgcn_mfma_f32_16x16x32_bf16(A2l, W2f[ks][1], p1, 0, 0, 0);
        }
        // layer 3: relu + dot(W3), reduce over the 16 cols (l15)
        float sv[4];
        #pragma unroll
        for (int r = 0; r < 4; ++r)
            sv[r] = fmaxf(p0[r] + b2a, 0.f) * w3a + fmaxf(p1[r] + b2b, 0.f) * w3b;
        #pragma unroll
        for (int off = 1; off < 16; off <<= 1) {
            #pragma unroll
            for (int r = 0; r < 4; ++r) sv[r] += __shfl_xor(sv[r], off);
        }
        // broadcast: lane needs score of t0+l15 (lives in quad l15>>2, reg l15&3)
        const int src = (l15 >> 2) * 16;
        const float s0 = __shfl(sv[0], src), s1 = __shfl(sv[1], src);
        const float s2 = __shfl(sv[2], src), s3 = __shfl(sv[3], src);
        const int rr = l15 & 3;
        const float sres = (rr == 0) ? s0 : (rr == 1) ? s1 : (rr == 2) ? s2 : s3;
        float x;
        if (t < 200) x = (kidA != 0) ? (sres + b3v) : NEG_INF_F;
        else         x = -__builtin_inff();
        // online softmax update (cross-lane within 16-lane groups)
        float tmax = x;
        #pragma unroll
        for (int off = 1; off < 16; off <<= 1) tmax = fmaxf(tmax, __shfl_xor(tmax, off));
        const float mnew  = fmaxf(mrun, tmax);
        const float alpha = __expf(mrun - mnew);
        const float w     = __expf(x - mnew);
        float tsum = w;
        #pragma unroll
        for (int off = 1; off < 16; off <<= 1) tsum += __shfl_xor(tsum, off);
        lrun = lrun * alpha + tsum;
        mrun = mnew;
        #pragma unroll
        for (int ks = 0; ks < 4; ++ks) {
            O[ks*8+0] = fmaf(O[ks*8+0], alpha, w * kaA[ks].x);
            O[ks*8+1] = fmaf(O[ks*8+1], alpha, w * kaA[ks].y);
            O[ks*8+2] = fmaf(O[ks*8+2], alpha, w * kaA[ks].z);
            O[ks*8+3] = fmaf(O[ks*8+3], alpha, w * kaA[ks].w);
            O[ks*8+4] = fmaf(O[ks*8+4], alpha, w * kbA[ks].x);
            O[ks*8+5] = fmaf(O[ks*8+5], alpha, w * kbA[ks].y);
            O[ks*8+6] = fmaf(O[ks*8+6], alpha, w * kbA[ks].z);
            O[ks*8+7] = fmaf(O[ks*8+7], alpha, w * kbA[ks].w);
        }
        if (nx < 13) {
            #pragma unroll
            for (int ks = 0; ks < 4; ++ks) { kaA[ks] = kaB[ks]; kbA[ks] = kbB[ks]; }
            kidA = kidB;
        }
    }

    // intra-wave reduce of O over l15 (each quad owns cols ks*32+quad*8..+7)
    #pragma unroll
    for (int off = 1; off < 16; off <<= 1) {
        #pragma unroll
        for (int i = 0; i < 32; ++i) O[i] += __shfl_xor(O[i], off);
    }
    if (l15 == 0) {
        #pragma unroll
        for (int ks = 0; ks < 4; ++ks) {
            *reinterpret_cast<float4*>(&sm.Om[wave][ks * 32 + quad * 8]) =
                make_float4(O[ks*8+0], O[ks*8+1], O[ks*8+2], O[ks*8+3]);
            *reinterpret_cast<float4*>(&sm.Om[wave][ks * 32 + quad * 8 + 4]) =
                make_float4(O[ks*8+4], O[ks*8+5], O[ks*8+6], O[ks*8+7]);
        }
    }
    if (lane == 0) { sm.mw[wave] = mrun; sm.lw[wave] = lrun; }
    __syncthreads();

    // ---- merge 4 waves' online states, normalize, store ----
    if (tid < 128) {
        const float M = fmaxf(fmaxf(sm.mw[0], sm.mw[1]), fmaxf(sm.mw[2], sm.mw[3]));
        float den = 0.f, val = 0.f;
        #pragma unroll
        for (int w = 0; w < 4; ++w) {
            const float a = __expf(sm.mw[w] - M);
            den += sm.lw[w] * a;
            val += sm.Om[w][tid] * a;
        }
        out[(size_t)b * 128 + tid] = val / (den * 200.0f);  // softmax norm + mean(/T)
    }
}

extern "C" void kernel_launch(void* const* d_in, const int* in_sizes, int n_in,
                              void* d_out, int out_size, void* d_ws, size_t ws_size,
                              hipStream_t stream) {
    (void)in_sizes; (void)n_in; (void)out_size; (void)ws_size;
    float*          c_all = (float*)d_ws;                                  // 512 KB
    unsigned short* M_all = (unsigned short*)((char*)d_ws + (1 << 19));    // 33.5 MB

    precompute_cm<<<dim3(2048), dim3(256), 0, stream>>>(
        (const float*)d_in[0], (const float*)d_in[3], (const float*)d_in[4],
        c_all, M_all);
    attn_main<<<dim3(2048), dim3(256), 0, stream>>>(
        (const float*)d_in[1], (const int*)d_in[2],
        (const float*)d_in[5], (const float*)d_in[6],
        (const float*)d_in[7], (const float*)d_in[8],
        c_all, M_all, (float*)d_out);
}

// Round 8
// 355.690 us; speedup vs baseline: 1.2400x; 1.2400x over previous
//
#include <hip/hip_runtime.h>
#include <hip/hip_bf16.h>

#define NEG_INF_F (-4294967295.0f)  // -(2^32)+1, matches reference padding

typedef __attribute__((ext_vector_type(8))) short bf16x8;   // MFMA A/B frag (4 VGPRs)
typedef __attribute__((ext_vector_type(4))) float f32x4;    // MFMA C/D frag

__device__ __forceinline__ unsigned short f2bf(float x) {
    unsigned u = __float_as_uint(x);
    return (unsigned short)((u + 0x7fffu + ((u >> 16) & 1u)) >> 16);  // RNE
}
__device__ __forceinline__ unsigned f2bf2(float a, float b) {
    __hip_bfloat162 h2 = __float22bfloat162_rn(make_float2(a, b));
    unsigned r; __builtin_memcpy(&r, &h2, 4); return r;
}
union FragU { unsigned u[4]; bf16x8 h; };

// One-pass design, K streamed HBM->regs once, unnormalized-exp softmax
// (scores are O(1); masked rows exp(-4.3e9)=0, pad rows exp(-inf)=0).
// LDS 26.7 KB -> 4+ blocks/CU co-resident.
struct __align__(16) Smem {
    unsigned short Mt[64 * 128];    // 16384 B  M^T bf16 [n][k], swizzle g=(k>>3)^(n&15)
    unsigned short h1s[4][16 * 64]; //  8192 B  per-wave h1 C->A scratch
    float q[128];                   //   512 B
    float cpart[256];               //  1024 B  4 partial chunks of c[n]
    float Om[4][128];               //  2048 B  per-wave pooled partials (unnormalized)
    float lw[4];                    //    16 B  per-wave denominator partials
};

// 2nd arg = min BLOCKS/CU on this toolchain (R3 evidence). (256,4): VGPR cap
// 128 (R6 natural was 84 -> no spill), 16 waves/CU target (R6 measured 9.6).
__global__ __launch_bounds__(256, 4)
void attn_fused(const float* __restrict__ Q,    // [2048,128]
                const float* __restrict__ Kg,   // [2048,200,128]
                const int*   __restrict__ kid,  // [2048,200]
                const float* __restrict__ W1,   // [512,64]
                const float* __restrict__ b1,   // [64]
                const float* __restrict__ W2,   // [64,32]
                const float* __restrict__ b2,   // [32]
                const float* __restrict__ W3,   // [32,1]
                const float* __restrict__ b3,   // [1]
                float* __restrict__ out)        // [2048,128]
{
    __shared__ Smem sm;
    const int b    = blockIdx.x;
    const int tid  = threadIdx.x;
    const int wave = tid >> 6;
    const int lane = tid & 63;
    const int l15  = lane & 15;
    const int quad = lane >> 4;

    if (tid < 128) sm.q[tid] = Q[b * 128 + tid];

    // W2 B-frags + layer-3 consts (L2-hot, overlaps q latency)
    bf16x8 W2f[2][2];
    #pragma unroll
    for (int ks = 0; ks < 2; ++ks) {
        #pragma unroll
        for (int nt = 0; nt < 2; ++nt) {
            const int n = nt * 16 + l15;
            const int kb = ks * 32 + quad * 8;
            bf16x8 f;
            #pragma unroll
            for (int j = 0; j < 8; ++j) f[j] = (short)f2bf(W2[(kb + j) * 32 + n]);
            W2f[ks][nt] = f;
        }
    }
    const float w3a = W3[l15],  w3b = W3[16 + l15];
    const float b2a = b2[l15],  b2b = b2[16 + l15];
    const float b3v = b3[0];
    __syncthreads();

    // ---- cooperative M build: M[k][n] = (W1k-W1d)[k][n] + q[k]*W1p[k][n] ----
    // stored transposed Mt[n][k], bf16, granule swizzle g=(k>>3)^(n&15).
    {
        const int n  = tid & 63;
        const int ko = (tid >> 6) * 2;
        #pragma unroll
        for (int i = 0; i < 16; ++i) {
            const int k = i * 8 + ko;
            const float v0 = (W1[(128 + k) * 64 + n] - W1[(256 + k) * 64 + n])
                           + sm.q[k] * W1[(384 + k) * 64 + n];
            const float v1 = (W1[(129 + k) * 64 + n] - W1[(257 + k) * 64 + n])
                           + sm.q[k + 1] * W1[(385 + k) * 64 + n];
            const int g = (k >> 3) ^ (n & 15);
            *reinterpret_cast<unsigned*>(&sm.Mt[n * 128 + g * 8 + (k & 7)]) = f2bf2(v0, v1);
        }
    }
    // c[n] partials: wave w does 32 k's
    {
        const int n = tid & 63, kc = tid >> 6;
        float acc = (kc == 0) ? b1[n] : 0.0f;
        #pragma unroll 4
        for (int i = 0; i < 32; ++i) {
            const int k = kc * 32 + i;
            acc += sm.q[k] * (W1[k * 64 + n] + W1[(256 + k) * 64 + n]);
        }
        sm.cpart[kc * 64 + n] = acc;
    }
    __syncthreads();

    float cn[4];
    #pragma unroll
    for (int nt = 0; nt < 4; ++nt) {
        const int n = nt * 16 + l15;
        cn[nt] = sm.cpart[n] + sm.cpart[64 + n] + sm.cpart[128 + n] + sm.cpart[192 + n];
    }

    const float* kbase = Kg + (size_t)b * 25600;
    unsigned short* h1w = &sm.h1s[wave][0];
    const f32x4 zero4 = {0.f, 0.f, 0.f, 0.f};

    float O[32];
    #pragma unroll
    for (int i = 0; i < 32; ++i) O[i] = 0.0f;
    float lsum = 0.0f;   // per-lane: sum of w over this lane's t's

    // ---- tile loop: wave w does tiles w, w+4, w+8 (w==0 also 12) ----
    for (int tile = wave; tile < 13; tile += 4) {
        const int t0 = tile * 16;
        const int t  = t0 + l15;
        const int tr = min(t, 199);               // clamp OOB rows (tile 12)
        const float* kr = kbase + tr * 128;
        float4 ka[4], kb_[4];
        #pragma unroll
        for (int ks = 0; ks < 4; ++ks) {
            ka[ks]  = *reinterpret_cast<const float4*>(kr + ks * 32 + quad * 8);
            kb_[ks] = *reinterpret_cast<const float4*>(kr + ks * 32 + quad * 8 + 4);
        }
        const int kidv = kid[b * 200 + tr];

        f32x4 acc[4] = {zero4, zero4, zero4, zero4};
        #pragma unroll
        for (int ks = 0; ks < 4; ++ks) {
            FragU A;
            A.u[0] = f2bf2(ka[ks].x,  ka[ks].y);
            A.u[1] = f2bf2(ka[ks].z,  ka[ks].w);
            A.u[2] = f2bf2(kb_[ks].x, kb_[ks].y);
            A.u[3] = f2bf2(kb_[ks].z, kb_[ks].w);
            #pragma unroll
            for (int nt = 0; nt < 4; ++nt) {
                const int n = nt * 16 + l15;
                const int g = (ks * 4 + quad) ^ l15;
                const bf16x8 Bf = *reinterpret_cast<const bf16x8*>(&sm.Mt[n * 128 + g * 8]);
                acc[nt] = __builtin_amdgcn_mfma_f32_16x16x32_bf16(A.h, Bf, acc[nt], 0, 0, 0);
            }
        }
        // epilogue: + c[n], relu, bf16 -> wave-private scratch in A-layout
        #pragma unroll
        for (int nt = 0; nt < 4; ++nt) {
            const int n = nt * 16 + l15;
            #pragma unroll
            for (int r = 0; r < 4; ++r) {
                const int m = quad * 4 + r;
                const float h = fmaxf(acc[nt][r] + cn[nt], 0.0f);
                const int g = (n >> 3) ^ (m & 7);
                h1w[m * 64 + g * 8 + (n & 7)] = f2bf(h);
            }
        }
        // layer 2: [16,64] @ [64,32]
        f32x4 p0 = zero4, p1 = zero4;
        #pragma unroll
        for (int ks = 0; ks < 2; ++ks) {
            const int g = (ks * 4 + quad) ^ (l15 & 7);
            const bf16x8 A2l = *reinterpret_cast<const bf16x8*>(&h1w[l15 * 64 + g * 8]);
            p0 = __builtin_amdgcn_mfma_f32_16x16x32_bf16(A2l, W2f[ks][0], p0, 0, 0, 0);
            p1 = __builtin_amdgcn_mfma_f32_16x16x32_bf16(A2l, W2f[ks][1], p1, 0, 0, 0);
        }
        // layer 3: relu + dot(W3), reduce over the 16 cols (l15)
        float sv[4];
        #pragma unroll
        for (int r = 0; r < 4; ++r)
            sv[r] = fmaxf(p0[r] + b2a, 0.f) * w3a + fmaxf(p1[r] + b2b, 0.f) * w3b;
        #pragma unroll
        for (int off = 1; off < 16; off <<= 1) {
            #pragma unroll
            for (int r = 0; r < 4; ++r) sv[r] += __shfl_xor(sv[r], off);
        }
        // broadcast: lane needs score of t0+l15 (lives in quad l15>>2, reg l15&3)
        const int src = (l15 >> 2) * 16;
        const float s0 = __shfl(sv[0], src), s1 = __shfl(sv[1], src);
        const float s2 = __shfl(sv[2], src), s3 = __shfl(sv[3], src);
        const int rr = l15 & 3;
        const float sres = (rr == 0) ? s0 : (rr == 1) ? s1 : (rr == 2) ? s2 : s3;
        float x;
        if (t < 200) x = (kidv != 0) ? (sres + b3v) : NEG_INF_F;
        else         x = -__builtin_inff();
        // unnormalized softmax: w = exp(x); masked/pad rows give w == 0
        const float w = __expf(x);
        lsum += w;
        #pragma unroll
        for (int ks = 0; ks < 4; ++ks) {
            O[ks*8+0] = fmaf(w, ka[ks].x,  O[ks*8+0]);
            O[ks*8+1] = fmaf(w, ka[ks].y,  O[ks*8+1]);
            O[ks*8+2] = fmaf(w, ka[ks].z,  O[ks*8+2]);
            O[ks*8+3] = fmaf(w, ka[ks].w,  O[ks*8+3]);
            O[ks*8+4] = fmaf(w, kb_[ks].x, O[ks*8+4]);
            O[ks*8+5] = fmaf(w, kb_[ks].y, O[ks*8+5]);
            O[ks*8+6] = fmaf(w, kb_[ks].z, O[ks*8+6]);
            O[ks*8+7] = fmaf(w, kb_[ks].w, O[ks*8+7]);
        }
    }

    // intra-wave reduce over l15 (each quad owns cols ks*32+quad*8..+7; the
    // 4 quads hold identical t-sets, so lsum reduces within 16 lanes only)
    #pragma unroll
    for (int off = 1; off < 16; off <<= 1) {
        lsum += __shfl_xor(lsum, off);
        #pragma unroll
        for (int i = 0; i < 32; ++i) O[i] += __shfl_xor(O[i], off);
    }
    if (l15 == 0) {
        #pragma unroll
        for (int ks = 0; ks < 4; ++ks) {
            *reinterpret_cast<float4*>(&sm.Om[wave][ks * 32 + quad * 8]) =
                make_float4(O[ks*8+0], O[ks*8+1], O[ks*8+2], O[ks*8+3]);
            *reinterpret_cast<float4*>(&sm.Om[wave][ks * 32 + quad * 8 + 4]) =
                make_float4(O[ks*8+4], O[ks*8+5], O[ks*8+6], O[ks*8+7]);
        }
    }
    if (lane == 0) sm.lw[wave] = lsum;
    __syncthreads();

    // ---- merge 4 waves' partials, normalize, store ----
    if (tid < 128) {
        const float den = sm.lw[0] + sm.lw[1] + sm.lw[2] + sm.lw[3];
        const float val = sm.Om[0][tid] + sm.Om[1][tid] + sm.Om[2][tid] + sm.Om[3][tid];
        out[(size_t)b * 128 + tid] = val / (den * 200.0f);  // softmax norm + mean(/T)
    }
}

extern "C" void kernel_launch(void* const* d_in, const int* in_sizes, int n_in,
                              void* d_out, int out_size, void* d_ws, size_t ws_size,
                              hipStream_t stream) {
    (void)in_sizes; (void)n_in; (void)out_size; (void)d_ws; (void)ws_size;
    attn_fused<<<dim3(2048), dim3(256), 0, stream>>>(
        (const float*)d_in[0], (const float*)d_in[1], (const int*)d_in[2],
        (const float*)d_in[3], (const float*)d_in[4], (const float*)d_in[5],
        (const float*)d_in[6], (const float*)d_in[7], (const float*)d_in[8],
        (float*)d_out);
}